// Round 8
// baseline (411.887 us; speedup 1.0000x reference)
//
#include <hip/hip_runtime.h>
#include <hip/hip_bf16.h>
#include <stdint.h>

#define HP 58
#define WP 64
#define CIN 256
#define COUT 256
#define HH 56
#define WW 56
#define IMG_STRIDE (HP*WP*CIN)   // bytes per image in xb (i8): 950272
#define ROW_STRIDE (WP*CIN)      // bytes per padded row in xb: 16384
#define NPIX 200704.0            // 64*56*56

// conv LDS layout (dynamic, 157952 B):
//   [0,256)          guard (x_in = -1 reads)
//   [256,59648)      X: 4 rows x 58 cols x 256B (row stride 14848), col-swizzled
//   [59648,157952)   per-wave A rings: 8 waves x 3 bufs x 4096 B
//                    (x_in >= 58 overrun reads land in ring area -> discarded outputs)
#define XO    256
#define XROW  14848
#define XBYTES (4*XROW)          // 59392
#define AO    59648
#define AWAVE 12288
#define LDS_TOTAL 157952

typedef __attribute__((ext_vector_type(4))) int i32x4;

#define GLDS(g, l) __builtin_amdgcn_global_load_lds( \
    (const __attribute__((address_space(1))) void*)(g), \
    (__attribute__((address_space(3))) void*)(l), 16, 0, 0)

// ---------- K1: per-(channel,image) partial sums in fp64 (deterministic) ----------
__global__ __launch_bounds__(256) void stats_partial(const float* __restrict__ x,
                                                     double* __restrict__ part) {
  int b = blockIdx.x;            // 256*64
  int c = b >> 6, n = b & 63;
  const float4* p = (const float4*)(x + (size_t)(n*CIN + c) * (HH*WW));
  double s = 0.0, s2 = 0.0;
  for (int i = threadIdx.x; i < 784; i += 256) {
    float4 v = p[i];
    double a0 = v.x, a1 = v.y, a2 = v.z, a3 = v.w;
    s  += (a0 + a1) + (a2 + a3);
    s2 += (a0*a0 + a1*a1) + (a2*a2 + a3*a3);
  }
  for (int off = 32; off > 0; off >>= 1) {
    s  += __shfl_down(s, off);
    s2 += __shfl_down(s2, off);
  }
  __shared__ double red[8];
  int wv = threadIdx.x >> 6, ln = threadIdx.x & 63;
  if (ln == 0) { red[wv*2] = s; red[wv*2+1] = s2; }
  __syncthreads();
  if (threadIdx.x == 0) {
    double ts = ((red[0]+red[2])+red[4])+red[6];
    double t2 = ((red[1]+red[3])+red[5])+red[7];
    part[(size_t)(c*64 + n)*2]     = ts;
    part[(size_t)(c*64 + n)*2 + 1] = t2;
  }
}

// ---------- K2: finalize per-channel {mean, gamma*inv_std, beta} in fp64 ----------
__global__ void stats_final(const double* __restrict__ part,
                            const float* __restrict__ gamma,
                            const float* __restrict__ beta,
                            double* __restrict__ prm) {
  int c = threadIdx.x;
  double s = 0.0, s2 = 0.0;
  for (int n = 0; n < 64; ++n) {
    s  += part[(size_t)(c*64+n)*2];
    s2 += part[(size_t)(c*64+n)*2 + 1];
  }
  double mean = s / NPIX;
  double var  = s2 / NPIX - mean*mean;
  double inv  = 1.0 / sqrt(var + 1e-5);
  prm[c*4+0] = mean;
  prm[c*4+1] = (double)gamma[c] * inv;
  prm[c*4+2] = (double)beta[c];
}

// ---------- K3: binarize + transpose to padded NHWC64 int8 (float4 reads) ----------
__global__ __launch_bounds__(256) void binarize(const float* __restrict__ x,
                                                const double* __restrict__ prm,
                                                int8_t* __restrict__ xb) {
  int b = blockIdx.x;            // 64*58
  int n = b / HP, y = b % HP;
  int8_t* orow = xb + (size_t)(n*HP + y) * ROW_STRIDE;
  if (y == 0 || y == HP-1) {     // zero padding rows: 16384 B
    int4 z = {0,0,0,0};
    int4* q = (int4*)orow;
    for (int i = threadIdx.x; i < ROW_STRIDE/16; i += 256) q[i] = z;
    return;
  }
  __shared__ char sbuf[WW][260];   // odd dword stride -> conflict-free
  int h  = y - 1;
  int tid = threadIdx.x;
  #pragma unroll
  for (int it = 0; it < 14; ++it) {        // 14*256 = 3584 = 256c * 14 float4
    int t = it*256 + tid;
    int c = t / 14, j = t - c*14;
    float4 v = *(const float4*)(x + (size_t)(n*CIN + c)*(HH*WW) + h*WW + j*4);
    double mu = prm[c*4], gi = prm[c*4+1], be = prm[c*4+2];
    #pragma unroll
    for (int e = 0; e < 4; ++e) {
      double xv = (double)((&v.x)[e]);
      double vv = (xv - mu)*gi + be;
      sbuf[j*4+e][c] = vv > 0.0 ? (int8_t)1 : (vv < 0.0 ? (int8_t)-1 : (int8_t)0);
    }
  }
  __syncthreads();
  int xh = tid >> 6, cq = tid & 63;
  uint32_t* orow32 = (uint32_t*)orow;
  for (int xx0 = 0; xx0 < WP; xx0 += 4) {
    int xx = xx0 + xh;
    uint32_t v = 0;
    if (xx >= 1 && xx <= WW) v = *(const uint32_t*)&sbuf[xx-1][cq*4];
    orow32[xx*64 + cq] = v;
  }
}

// ---------- K4: quantize W[co][ci][3][3] fp32 -> Wb[tap][co][ci] i8, per-co scale ----------
__global__ __launch_bounds__(256) void wrepack(const float* __restrict__ W,
                                               int8_t* __restrict__ Wb,
                                               float* __restrict__ invs) {
  int co = blockIdx.x, ci = threadIdx.x;
  float w[9]; float mx = 0.f;
  const float* p = W + (size_t)co*(CIN*9) + ci*9;
  #pragma unroll
  for (int t = 0; t < 9; ++t) { w[t] = p[t]; mx = fmaxf(mx, fabsf(w[t])); }
  for (int off = 32; off > 0; off >>= 1) mx = fmaxf(mx, __shfl_xor(mx, off));
  __shared__ float sm[4];
  if ((threadIdx.x & 63) == 0) sm[threadIdx.x >> 6] = mx;
  __syncthreads();
  mx = fmaxf(fmaxf(sm[0], sm[1]), fmaxf(sm[2], sm[3]));
  float s = mx > 0.f ? 127.f / mx : 0.f;
  #pragma unroll
  for (int t = 0; t < 9; ++t) {
    int q = (int)lrintf(w[t] * s);
    q = q > 127 ? 127 : (q < -127 ? -127 : q);
    Wb[t*(COUT*CIN) + co*CIN + ci] = (int8_t)q;
  }
  if (threadIdx.x == 0) invs[co] = mx / 127.f;
}

// ---------- K5: implicit-GEMM conv, int8, WAVE-ASYNC: no in-loop barriers ----------
// Tile 256co x (2 rows x 64 xx); 8 waves = 4 wm (64co) x 2 wn (row). X resident+shared
// (read-only). Each wave stages its OWN A-slice (64co x 64ci) into a private 3-deep ring;
// sync is per-wave vmcnt/lgkm only. Register cur/next pipeline: LOADF(s+1) issued during
// MFMA(s); ring overwrite (s+3) after MFMA cluster (auto-lgkm proves reads of s done).
__global__ __launch_bounds__(512, 2) void conv_gemm(const int8_t* __restrict__ xb,
                                                    const int8_t* __restrict__ Wb,
                                                    const float* __restrict__ invs,
                                                    float* __restrict__ out) {
  extern __shared__ char smem[];
  int bid = blockIdx.x;
  int swz = (bid & 7) * 224 + (bid >> 3);    // XCD-aware, bijective (1792 % 8 == 0)
  int n_img = swz / 28, rg = swz - n_img * 28;
  int y0 = 1 + rg * 2;                       // output rows y0, y0+1 (padded coords)

  int tid = threadIdx.x;
  int ln = tid & 63, wid = tid >> 6;
  int wm = wid >> 1, wn = wid & 1;           // wm: 64co slice, wn: y-row

  size_t xoff = (size_t)n_img * IMG_STRIDE + (size_t)(y0 - 1) * ROW_STRIDE;

  // ---- prologue: stage X once (4 rows x 58 x 256B), pre-swizzled source ----
  #pragma unroll
  for (int i = 0; i < 8; ++i) {
    int o = tid*16 + i*8192;
    if (o < XBYTES) {                        // last iter: tids 0..127 only (wave-uniform)
      int r   = o / XROW;
      int rem = o - r*XROW;
      int xx  = rem >> 8, cb = rem & 255;
      const int8_t* src = xb + xoff + r*ROW_STRIDE + xx*256 + (cb ^ ((xx & 7) << 4));
      GLDS(src, smem + XO + o);
    }
  }

  // ---- per-wave private A staging: 64co x 64ci -> 4 GLDS (kslice-major 4 x 1KB) ----
  char* aring = smem + AO + wid * AWAVE;
  auto STAGE_A = [&](int s) {
    int sc = s < 36 ? s : 35;                // tail clamp (source only)
    int tap = sc >> 2, ci0 = (sc & 3) << 6;
    const int8_t* src = Wb + tap*(COUT*CIN) + (size_t)(wm*64 + ln)*CIN + ci0;
    char* dst = aring + (s % 3) * 4096;      // HW: dest = uniform base + lane*16
    GLDS(src,      dst);
    GLDS(src + 16, dst + 1024);
    GLDS(src + 32, dst + 2048);
    GLDS(src + 48, dst + 3072);
  };

  i32x4 acc[4][4] = {};
  STAGE_A(0); STAGE_A(1); STAGE_A(2);
  asm volatile("s_waitcnt vmcnt(12)" ::: "memory");   // X landed (A 12 in flight)
  __builtin_amdgcn_s_barrier();                       // the ONLY barrier before epilogue

  // A-frag: byte = kslice(ln>>4)*1024 + (m*16 + (ln&15))*16
  int afrag = ((ln >> 4) << 10) + (ln & 15) * 16;
  int xx0   = ln & 15;
  int cb16  = (ln >> 4) << 4;

  auto LOADF = [&](int s, i32x4 (&av)[4], i32x4 (&bv)[4]) {
    int sc = s < 36 ? s : 35;
    const char* Ab = aring + (s % 3) * 4096 + afrag;
    #pragma unroll
    for (int m = 0; m < 4; ++m) av[m] = *(const i32x4*)(Ab + m*256);
    int tap = sc >> 2;
    int kh = (tap * 11) >> 5, kw = tap - kh * 3;
    int cb = ((sc & 3) << 6) + cb16;
    const char* Xr = smem + XO + (wn + kh) * XROW;
    #pragma unroll
    for (int nn = 0; nn < 4; ++nn) {
      int x_in = xx0 + nn*16 + kw - 1;
      bv[nn] = *(const i32x4*)(Xr + x_in*256 + (cb ^ ((x_in & 7) << 4)));
    }
  };

  i32x4 aR[2][4], bR[2][4];
  asm volatile("s_waitcnt vmcnt(8)" ::: "memory");    // A(0) landed
  LOADF(0, aR[0], bR[0]);

  auto body = [&](int s, i32x4 (&ca)[4], i32x4 (&cb_)[4], i32x4 (&na)[4], i32x4 (&nb)[4]) {
    asm volatile("s_waitcnt vmcnt(4)" ::: "memory");  // A(s+1) landed (A(s+2) in flight)
    LOADF(s + 1, na, nb);                             // issue; consumed next body
    __builtin_amdgcn_s_setprio(1);
    #pragma unroll
    for (int m = 0; m < 4; ++m)                       // compiler's lgkm wait here proves
      #pragma unroll                                  // LOADF(s) reads (buf s%3) complete
      for (int nn = 0; nn < 4; ++nn)
        acc[m][nn] = __builtin_amdgcn_mfma_i32_16x16x64_i8(ca[m], cb_[nn], acc[m][nn], 0, 0, 0);
    __builtin_amdgcn_s_setprio(0);
    asm volatile("" ::: "memory");                    // keep GLDS below the reads' consumption
    STAGE_A(s + 3);                                   // overwrite buf s%3 (reads done)
  };

  #pragma unroll 1
  for (int t = 0; t < 18; ++t) {
    body(2*t,     aR[0], bR[0], aR[1], bR[1]);
    body(2*t + 1, aR[1], bR[1], aR[0], bR[0]);
  }

  // ---------------- epilogue: per-wave 64x64 LDS transpose -> coalesced dwordx4 ----
  asm volatile("s_waitcnt vmcnt(0) lgkmcnt(0)" ::: "memory");
  __builtin_amdgcn_s_barrier();                       // all waves done with X/A regions

  float ivv[4][4];
  #pragma unroll
  for (int m = 0; m < 4; ++m)
    #pragma unroll
    for (int r = 0; r < 4; ++r)
      ivv[m][r] = invs[wm*64 + m*16 + (ln >> 4)*4 + r];

  char* eb = smem + wid * 16384;               // 8 x 16KB = 128KB <= 157952
  int co0 = wm * 64;
  size_t obase = (size_t)n_img * COUT * (HH*WW) + (size_t)(y0 + wn - 1) * WW;

  #pragma unroll
  for (int m = 0; m < 4; ++m)
    #pragma unroll
    for (int nn = 0; nn < 4; ++nn)
      #pragma unroll
      for (int r = 0; r < 4; ++r) {
        int row  = m*16 + (ln >> 4)*4 + r;
        int slot = (nn*16 + (ln & 15) + 63) & 63;    // xx -> x=xx-1 (xx=0 parks at 63)
        int q    = (row >> 2) & 3;
        float v = fmaxf((float)acc[m][nn][r] * ivv[m][r], 0.0f);
        *(float*)(eb + row*256 + ((slot ^ (q << 4)) << 2)) = v;
      }
  asm volatile("s_waitcnt lgkmcnt(0)" ::: "memory");  // eb is wave-private: no barrier
  int c16 = ln & 15, rq = ln >> 4;
  #pragma unroll
  for (int j = 0; j < 16; ++j) {
    int row = j*4 + rq;
    int q   = (row >> 2) & 3;
    float4 v = *(const float4*)(eb + row*256 + ((c16 << 4) ^ (q << 6)));
    if (c16 < 14)
      *(float4*)(out + obase + (size_t)(co0 + row)*(HH*WW) + c16*4) = v;
  }
}

extern "C" void kernel_launch(void* const* d_in, const int* in_sizes, int n_in,
                              void* d_out, int out_size, void* d_ws, size_t ws_size,
                              hipStream_t stream) {
  const float* x     = (const float*)d_in[0];
  const float* gamma = (const float*)d_in[1];
  const float* beta  = (const float*)d_in[2];
  const float* W     = (const float*)d_in[3];
  float* out = (float*)d_out;

  char* ws = (char*)d_ws;
  // layout: part [262144] | prm [8192] | invs [1024] | Wb i8 [589824] | pad | xb i8 @1MiB
  double*  part = (double*)ws;
  double*  prm  = (double*)(ws + 262144);
  float*   invs = (float*)(ws + 270336);
  int8_t*  Wb   = (int8_t*)(ws + 271360);
  int8_t*  xbuf = (int8_t*)(ws + 1048576);
  // xb: 64*58*64*256 = 60,817,408 B

  (void)hipFuncSetAttribute((const void*)conv_gemm,
                            hipFuncAttributeMaxDynamicSharedMemorySize, LDS_TOTAL);

  hipLaunchKernelGGL(wrepack,       dim3(256),    dim3(256), 0, stream, W, Wb, invs);
  hipLaunchKernelGGL(stats_partial, dim3(256*64), dim3(256), 0, stream, x, part);
  hipLaunchKernelGGL(stats_final,   dim3(1),      dim3(256), 0, stream, part, gamma, beta, prm);
  hipLaunchKernelGGL(binarize,      dim3(64*HP),  dim3(256), 0, stream, x, prm, xbuf);
  hipLaunchKernelGGL(conv_gemm,     dim3(1792),   dim3(512), LDS_TOTAL, stream, xbuf, Wb, invs, out);
}

// Round 9
// 283.228 us; speedup vs baseline: 1.4543x; 1.4543x over previous
//
#include <hip/hip_runtime.h>
#include <hip/hip_bf16.h>
#include <stdint.h>

#define HP 58
#define CIN 256
#define COUT 256
#define HH 56
#define WW 56
#define XROW 14848              // bytes per padded row in xb: 16 slots x 58 x 16B
#define IMG_STRIDE (HP*XROW)    // 861184 B per image
#define NPIX 200704.0           // 64*56*56

// conv LDS layout (dynamic, 155136 B):
//   [0,16)           front guard (x_in = -1, slot 0, row 0)
//   [16,89104)       X: 6 rows x 16 slots x 58 x 16B (row stride 14848, slot stride 928)
//   [89104,89600)    tail slack (x_in up to 64 bleeds reads here / into A ring: discarded)
//   [89600,155136)   A ring: 4 x 16384, slot-major: slot(4)*4096 + co(256)*16
#define XO    16
#define SROW  928
#define AO    89600
#define LDS_TOTAL 155136

typedef __attribute__((ext_vector_type(4)))  int i32x4;
typedef __attribute__((ext_vector_type(16))) int i32x16;

#define GLDS(g, l) __builtin_amdgcn_global_load_lds( \
    (const __attribute__((address_space(1))) void*)(g), \
    (__attribute__((address_space(3))) void*)(l), 16, 0, 0)

// ---------- K1: per-(channel,image) partial sums in fp64 (deterministic) ----------
__global__ __launch_bounds__(256) void stats_partial(const float* __restrict__ x,
                                                     double* __restrict__ part) {
  int b = blockIdx.x;            // 256*64
  int c = b >> 6, n = b & 63;
  const float4* p = (const float4*)(x + (size_t)(n*CIN + c) * (HH*WW));
  double s = 0.0, s2 = 0.0;
  for (int i = threadIdx.x; i < 784; i += 256) {
    float4 v = p[i];
    double a0 = v.x, a1 = v.y, a2 = v.z, a3 = v.w;
    s  += (a0 + a1) + (a2 + a3);
    s2 += (a0*a0 + a1*a1) + (a2*a2 + a3*a3);
  }
  for (int off = 32; off > 0; off >>= 1) {
    s  += __shfl_down(s, off);
    s2 += __shfl_down(s2, off);
  }
  __shared__ double red[8];
  int wv = threadIdx.x >> 6, ln = threadIdx.x & 63;
  if (ln == 0) { red[wv*2] = s; red[wv*2+1] = s2; }
  __syncthreads();
  if (threadIdx.x == 0) {
    double ts = ((red[0]+red[2])+red[4])+red[6];
    double t2 = ((red[1]+red[3])+red[5])+red[7];
    part[(size_t)(c*64 + n)*2]     = ts;
    part[(size_t)(c*64 + n)*2 + 1] = t2;
  }
}

// ---------- K2: finalize per-channel {mean, gamma*inv_std, beta} in fp64 ----------
__global__ void stats_final(const double* __restrict__ part,
                            const float* __restrict__ gamma,
                            const float* __restrict__ beta,
                            double* __restrict__ prm) {
  int c = threadIdx.x;
  double s = 0.0, s2 = 0.0;
  for (int n = 0; n < 64; ++n) {
    s  += part[(size_t)(c*64+n)*2];
    s2 += part[(size_t)(c*64+n)*2 + 1];
  }
  double mean = s / NPIX;
  double var  = s2 / NPIX - mean*mean;
  double inv  = 1.0 / sqrt(var + 1e-5);
  prm[c*4+0] = mean;
  prm[c*4+1] = (double)gamma[c] * inv;
  prm[c*4+2] = (double)beta[c];
}

// ---------- K3: binarize -> xb[n][y][slot16][x58][16B] int8 ----------
__global__ __launch_bounds__(256) void binarize(const float* __restrict__ x,
                                                const double* __restrict__ prm,
                                                int8_t* __restrict__ xb) {
  int b = blockIdx.x;            // 64*58
  int n = b / HP, y = b % HP;
  int8_t* orow = xb + (size_t)(n*HP + y) * XROW;
  if (y == 0 || y == HP-1) {     // zero padding rows: 14848 B
    int4 z = {0,0,0,0};
    int4* q = (int4*)orow;
    for (int i = threadIdx.x; i < XROW/16; i += 256) q[i] = z;
    return;
  }
  __shared__ char sbuf[WW][260];   // odd dword stride -> conflict-free
  int h  = y - 1;
  int tid = threadIdx.x;
  #pragma unroll
  for (int it = 0; it < 14; ++it) {        // 14*256 = 3584 = 256c * 14 float4
    int t = it*256 + tid;
    int c = t / 14, j = t - c*14;
    float4 v = *(const float4*)(x + (size_t)(n*CIN + c)*(HH*WW) + h*WW + j*4);
    double mu = prm[c*4], gi = prm[c*4+1], be = prm[c*4+2];
    #pragma unroll
    for (int e = 0; e < 4; ++e) {
      double xv = (double)((&v.x)[e]);
      double vv = (xv - mu)*gi + be;
      sbuf[j*4+e][c] = vv > 0.0 ? (int8_t)1 : (vv < 0.0 ? (int8_t)-1 : (int8_t)0);
    }
  }
  __syncthreads();
  // write: unit u = slot*58 + xx -> 16B of channels [slot*16, slot*16+16) at column xx
  for (int u = tid; u < 16*58; u += 256) {
    int slot = u / 58, xx = u - slot*58;
    int4 v = {0,0,0,0};
    if (xx >= 1 && xx <= WW) {
      const uint32_t* src = (const uint32_t*)&sbuf[xx-1][slot*16];
      v.x = src[0]; v.y = src[1]; v.z = src[2]; v.w = src[3];
    }
    *(int4*)(orow + u*16) = v;
  }
}

// ---------- K4: quantize W -> Wbr[tap][q4][slot4][co256][16B] i8, per-co scale ----------
__global__ __launch_bounds__(256) void wrepack(const float* __restrict__ W,
                                               int8_t* __restrict__ Wbr,
                                               float* __restrict__ invs) {
  int co = blockIdx.x, ci = threadIdx.x;
  float w[9]; float mx = 0.f;
  const float* p = W + (size_t)co*(CIN*9) + ci*9;
  #pragma unroll
  for (int t = 0; t < 9; ++t) { w[t] = p[t]; mx = fmaxf(mx, fabsf(w[t])); }
  for (int off = 32; off > 0; off >>= 1) mx = fmaxf(mx, __shfl_xor(mx, off));
  __shared__ float sm[4];
  if ((threadIdx.x & 63) == 0) sm[threadIdx.x >> 6] = mx;
  __syncthreads();
  mx = fmaxf(fmaxf(sm[0], sm[1]), fmaxf(sm[2], sm[3]));
  float s = mx > 0.f ? 127.f / mx : 0.f;
  int off = ((ci >> 6) * 4 + ((ci >> 4) & 3)) * 4096 + co*16 + (ci & 15);
  #pragma unroll
  for (int t = 0; t < 9; ++t) {
    int q = (int)lrintf(w[t] * s);
    q = q > 127 ? 127 : (q < -127 ? -127 : q);
    Wbr[t*65536 + off] = (int8_t)q;
  }
  if (threadIdx.x == 0) invs[co] = mx / 127.f;
}

// ---------- K5: implicit-GEMM conv, i8 32x32x32. X resident (transposed); A 4-ring ----------
// 8 waves = 2wm(128co) x 4wn(y-row); per wave 128co x 64xx = 4m x 2n tiles of 32.
// body(s): vmcnt(2) [A(s+1) landed]; barrier; STAGE_A(s+3); LOADF(s+1) (12 ds_read_b128,
// no drain); 16 mfma_i32_32x32x32_i8 on cur regs. Epilogue: direct coalesced stores.
__global__ __launch_bounds__(512, 2) void conv_gemm(const int8_t* __restrict__ xb,
                                                    const int8_t* __restrict__ Wbr,
                                                    const float* __restrict__ invs,
                                                    float* __restrict__ out) {
  extern __shared__ char smem[];
  int bid = blockIdx.x;
  int swz = (bid & 7) * 112 + (bid >> 3);    // XCD-aware, bijective (896 % 8 == 0)
  int n_img = swz / 14, rg = swz - n_img * 14;
  int y0 = 1 + rg * 4;                       // output rows y0..y0+3 (padded coords)

  int tid = threadIdx.x;
  int ln = tid & 63, wid = tid >> 6;
  int wm = wid >> 2, wn = wid & 3;           // wm: co half, wn: y-row

  size_t xoff = (size_t)n_img * IMG_STRIDE + (size_t)(y0 - 1) * XROW;

  // ---- prologue: stage X once, pure linear copy (6 rows x 14848 B = 89088 B) ----
  #pragma unroll
  for (int i = 0; i < 11; ++i) {
    int o = tid*16 + i*8192;
    if (o < 6*XROW)                          // 89088 = 87*1024: wave-uniform guard
      GLDS(xb + xoff + o, smem + XO + o);
  }

  // ---- A staging: linear 16KB copy from slot-major Wbr; 2 GLDS/thread ----
  auto STAGE_A = [&](int s, int buf) {
    int sc = s < 36 ? s : 35;                // tail clamp (source only)
    const int8_t* src = Wbr + (sc >> 2)*65536 + (sc & 3)*16384 + tid*16;
    char* dst = smem + AO + buf*16384 + tid*16;
    GLDS(src,        dst);
    GLDS(src + 8192, dst + 8192);
  };

  i32x16 acc[4][2] = {};
  STAGE_A(0, 0); STAGE_A(1, 1); STAGE_A(2, 2);

  // A-frag: byte = (ks*2 + (ln>>5))*4096 + (wm*128 + mt*32 + (ln&31))*16
  int afrag = ((ln >> 5) << 12) + (wm*128 + (ln & 31)) * 16;
  int xx0   = ln & 31;                       // + nt*32 + kw - 1
  int slotL = ln >> 5;

  i32x4 aR[2][4][2], bR[2][2][2];            // [set][tile][ks]

  auto LOADF = [&](int s, i32x4 (&av)[4][2], i32x4 (&bv)[2][2]) {
    int sc = s < 36 ? s : 35;
    const char* Ab = smem + AO + (s & 3)*16384 + afrag;
    #pragma unroll
    for (int mt = 0; mt < 4; ++mt)
      #pragma unroll
      for (int ks = 0; ks < 2; ++ks)
        av[mt][ks] = *(const i32x4*)(Ab + ks*8192 + mt*512);
    int tap = sc >> 2, q = sc & 3;
    int kh = (tap * 11) >> 5, kw = tap - kh * 3;
    const char* Xr = smem + XO + (wn + kh) * XROW;
    #pragma unroll
    for (int nt = 0; nt < 2; ++nt) {
      int x_in = xx0 + nt*32 + kw - 1;
      #pragma unroll
      for (int ks = 0; ks < 2; ++ks)
        bv[nt][ks] = *(const i32x4*)(Xr + (q*4 + ks*2 + slotL)*SROW + x_in*16);
    }
  };

  // prologue wait: X + A(0) landed (A1,A2 = 4 loads outstanding), then block sync
  asm volatile("s_waitcnt vmcnt(4)" ::: "memory");
  __builtin_amdgcn_s_barrier();
  LOADF(0, aR[0], bR[0]);

  auto body = [&](int s, i32x4 (&ca)[4][2], i32x4 (&cb)[2][2],
                         i32x4 (&na)[4][2], i32x4 (&nb)[2][2]) {
    asm volatile("s_waitcnt vmcnt(2)" ::: "memory");   // A(s+1) landed; barrier -> all waves
    __builtin_amdgcn_s_barrier();
    STAGE_A(s + 3, (s + 3) & 3);
    LOADF(s + 1, na, nb);                              // issue only; no drain
    __builtin_amdgcn_s_setprio(1);
    #pragma unroll
    for (int ks = 0; ks < 2; ++ks)
      #pragma unroll
      for (int mt = 0; mt < 4; ++mt)
        #pragma unroll
        for (int nt = 0; nt < 2; ++nt)
          acc[mt][nt] = __builtin_amdgcn_mfma_i32_32x32x32_i8(ca[mt][ks], cb[nt][ks],
                                                              acc[mt][nt], 0, 0, 0);
    __builtin_amdgcn_s_setprio(0);
  };

  #pragma unroll 1
  for (int t = 0; t < 18; ++t) {
    body(2*t,     aR[0], bR[0], aR[1], bR[1]);
    body(2*t + 1, aR[1], bR[1], aR[0], bR[0]);
  }
  asm volatile("s_waitcnt vmcnt(0)" ::: "memory");     // drain tail GLDS before exit

  // ---- epilogue: direct coalesced stores. C: col=ln&31 -> xx, row=(r&3)+8(r>>2)+4(ln>>5) ----
  int y_out = y0 + wn - 1;
  size_t ob0 = ((size_t)n_img * COUT) * (HH*WW) + (size_t)y_out * WW;
  #pragma unroll
  for (int mt = 0; mt < 4; ++mt) {
    int cb0 = wm*128 + mt*32 + ((ln >> 5) << 2);
    float4 iv[4];
    #pragma unroll
    for (int q = 0; q < 4; ++q) iv[q] = *(const float4*)(invs + cb0 + 8*q);
    #pragma unroll
    for (int nt = 0; nt < 2; ++nt) {
      int xx = nt*32 + (ln & 31);
      bool ok = (xx >= 1) && (xx <= WW);
      size_t ob = ob0 + (xx - 1);
      #pragma unroll
      for (int r = 0; r < 16; ++r) {
        int q = r >> 2, rr = r & 3;
        int co = cb0 + 8*q + rr;
        float v = fmaxf((float)acc[mt][nt][r] * ((&iv[q].x)[rr]), 0.0f);
        if (ok) out[ob + (size_t)co * (HH*WW)] = v;
      }
    }
  }
}

extern "C" void kernel_launch(void* const* d_in, const int* in_sizes, int n_in,
                              void* d_out, int out_size, void* d_ws, size_t ws_size,
                              hipStream_t stream) {
  const float* x     = (const float*)d_in[0];
  const float* gamma = (const float*)d_in[1];
  const float* beta  = (const float*)d_in[2];
  const float* W     = (const float*)d_in[3];
  float* out = (float*)d_out;

  char* ws = (char*)d_ws;
  // layout: part [262144] | prm [8192] | invs [1024] | Wbr i8 [589824] | pad | xb i8 @1MiB
  double*  part = (double*)ws;
  double*  prm  = (double*)(ws + 262144);
  float*   invs = (float*)(ws + 270336);
  int8_t*  Wbr  = (int8_t*)(ws + 271360);
  int8_t*  xbuf = (int8_t*)(ws + 1048576);
  // xb: 64*58*14848 = 55,115,776 B

  (void)hipFuncSetAttribute((const void*)conv_gemm,
                            hipFuncAttributeMaxDynamicSharedMemorySize, LDS_TOTAL);

  hipLaunchKernelGGL(wrepack,       dim3(256),    dim3(256), 0, stream, W, Wbr, invs);
  hipLaunchKernelGGL(stats_partial, dim3(256*64), dim3(256), 0, stream, x, part);
  hipLaunchKernelGGL(stats_final,   dim3(1),      dim3(256), 0, stream, part, gamma, beta, prm);
  hipLaunchKernelGGL(binarize,      dim3(64*HP),  dim3(256), 0, stream, x, prm, xbuf);
  hipLaunchKernelGGL(conv_gemm,     dim3(896),    dim3(512), LDS_TOTAL, stream, xbuf, Wbr, invs, out);
}

// Round 10
// 276.523 us; speedup vs baseline: 1.4895x; 1.0242x over previous
//
#include <hip/hip_runtime.h>
#include <hip/hip_bf16.h>
#include <stdint.h>

#define HP 58
#define CIN 256
#define COUT 256
#define HH 56
#define WW 56
#define XROW 14848              // bytes per padded row in xb: 16 slots x 58 x 16B
#define IMG_STRIDE (HP*XROW)    // 861184 B per image
#define NPIX 200704.0           // 64*56*56

// conv LDS layout (dynamic, 155136 B):
//   [0,16)           front guard (x_in = -1, slot 0, row 0)
//   [16,89104)       X: 6 rows x 16 slots x 58 x 16B (row stride 14848, slot stride 928)
//   [89104,89600)    tail slack (x_in up to 64 bleeds reads here: discarded outputs)
//   [89600,155136)   A ring: 4 x 16384 (ks*8192 + slotL*4096 + co*16)
#define XO    16
#define SROW  928
#define AO    89600
#define LDS_TOTAL 155136

typedef __attribute__((ext_vector_type(4)))  int i32x4;
typedef __attribute__((ext_vector_type(16))) int i32x16;

#define GLDS(g, l) __builtin_amdgcn_global_load_lds( \
    (const __attribute__((address_space(1))) void*)(g), \
    (__attribute__((address_space(3))) void*)(l), 16, 0, 0)

// ---------- K1: per-(channel,image) partial sums in fp64 (deterministic) ----------
__global__ __launch_bounds__(256) void stats_partial(const float* __restrict__ x,
                                                     double* __restrict__ part) {
  int b = blockIdx.x;            // 256*64
  int c = b >> 6, n = b & 63;
  const float4* p = (const float4*)(x + (size_t)(n*CIN + c) * (HH*WW));
  double s = 0.0, s2 = 0.0;
  for (int i = threadIdx.x; i < 784; i += 256) {
    float4 v = p[i];
    double a0 = v.x, a1 = v.y, a2 = v.z, a3 = v.w;
    s  += (a0 + a1) + (a2 + a3);
    s2 += (a0*a0 + a1*a1) + (a2*a2 + a3*a3);
  }
  for (int off = 32; off > 0; off >>= 1) {
    s  += __shfl_down(s, off);
    s2 += __shfl_down(s2, off);
  }
  __shared__ double red[8];
  int wv = threadIdx.x >> 6, ln = threadIdx.x & 63;
  if (ln == 0) { red[wv*2] = s; red[wv*2+1] = s2; }
  __syncthreads();
  if (threadIdx.x == 0) {
    double ts = ((red[0]+red[2])+red[4])+red[6];
    double t2 = ((red[1]+red[3])+red[5])+red[7];
    part[(size_t)(c*64 + n)*2]     = ts;
    part[(size_t)(c*64 + n)*2 + 1] = t2;
  }
}

// ---------- K2: finalize per-channel {mean, gamma*inv_std, beta} in fp64 ----------
__global__ void stats_final(const double* __restrict__ part,
                            const float* __restrict__ gamma,
                            const float* __restrict__ beta,
                            double* __restrict__ prm) {
  int c = threadIdx.x;
  double s = 0.0, s2 = 0.0;
  for (int n = 0; n < 64; ++n) {
    s  += part[(size_t)(c*64+n)*2];
    s2 += part[(size_t)(c*64+n)*2 + 1];
  }
  double mean = s / NPIX;
  double var  = s2 / NPIX - mean*mean;
  double inv  = 1.0 / sqrt(var + 1e-5);
  prm[c*4+0] = mean;
  prm[c*4+1] = (double)gamma[c] * inv;
  prm[c*4+2] = (double)beta[c];
}

// ---------- K3: binarize -> xb[n][y][slot16][x58][16B] int8 ----------
__global__ __launch_bounds__(256) void binarize(const float* __restrict__ x,
                                                const double* __restrict__ prm,
                                                int8_t* __restrict__ xb) {
  int b = blockIdx.x;            // 64*58
  int n = b / HP, y = b % HP;
  int8_t* orow = xb + (size_t)(n*HP + y) * XROW;
  if (y == 0 || y == HP-1) {     // zero padding rows: 14848 B
    int4 z = {0,0,0,0};
    int4* q = (int4*)orow;
    for (int i = threadIdx.x; i < XROW/16; i += 256) q[i] = z;
    return;
  }
  __shared__ char sbuf[WW][260];   // odd dword stride -> conflict-free
  int h  = y - 1;
  int tid = threadIdx.x;
  #pragma unroll
  for (int it = 0; it < 14; ++it) {        // 14*256 = 3584 = 256c * 14 float4
    int t = it*256 + tid;
    int c = t / 14, j = t - c*14;
    float4 v = *(const float4*)(x + (size_t)(n*CIN + c)*(HH*WW) + h*WW + j*4);
    double mu = prm[c*4], gi = prm[c*4+1], be = prm[c*4+2];
    #pragma unroll
    for (int e = 0; e < 4; ++e) {
      double xv = (double)((&v.x)[e]);
      double vv = (xv - mu)*gi + be;
      sbuf[j*4+e][c] = vv > 0.0 ? (int8_t)1 : (vv < 0.0 ? (int8_t)-1 : (int8_t)0);
    }
  }
  __syncthreads();
  // write: unit u = slot*58 + xx -> 16B of channels [slot*16, slot*16+16) at column xx
  for (int u = tid; u < 16*58; u += 256) {
    int slot = u / 58, xx = u - slot*58;
    int4 v = {0,0,0,0};
    if (xx >= 1 && xx <= WW) {
      const uint32_t* src = (const uint32_t*)&sbuf[xx-1][slot*16];
      v.x = src[0]; v.y = src[1]; v.z = src[2]; v.w = src[3];
    }
    *(int4*)(orow + u*16) = v;
  }
}

// ---------- K4: quantize W -> Wbr[tap][q4][ks2][slot2][co256][16B] i8, per-co scale ----------
__global__ __launch_bounds__(256) void wrepack(const float* __restrict__ W,
                                               int8_t* __restrict__ Wbr,
                                               float* __restrict__ invs) {
  int co = blockIdx.x, ci = threadIdx.x;
  float w[9]; float mx = 0.f;
  const float* p = W + (size_t)co*(CIN*9) + ci*9;
  #pragma unroll
  for (int t = 0; t < 9; ++t) { w[t] = p[t]; mx = fmaxf(mx, fabsf(w[t])); }
  for (int off = 32; off > 0; off >>= 1) mx = fmaxf(mx, __shfl_xor(mx, off));
  __shared__ float sm[4];
  if ((threadIdx.x & 63) == 0) sm[threadIdx.x >> 6] = mx;
  __syncthreads();
  mx = fmaxf(fmaxf(sm[0], sm[1]), fmaxf(sm[2], sm[3]));
  float s = mx > 0.f ? 127.f / mx : 0.f;
  int off = ((ci >> 6) * 4 + ((ci >> 4) & 3)) * 4096 + co*16 + (ci & 15);
  #pragma unroll
  for (int t = 0; t < 9; ++t) {
    int q = (int)lrintf(w[t] * s);
    q = q > 127 ? 127 : (q < -127 ? -127 : q);
    Wbr[t*65536 + off] = (int8_t)q;
  }
  if (threadIdx.x == 0) invs[co] = mx / 127.f;
}

// ---------- K5: implicit-GEMM conv, i8 32x32x32; tap-unrolled, literal-offset ds_reads ----
// 8 waves = 2wm(128co) x 4wn(y-row). Per step s=4t+q: vmcnt(2); barrier; STAGE(s+3);
// LOADF(s+1) (12 ds_read_b128, ALL literal offsets off 2 invariant VGPR bases);
// 16 mfma_i32_32x32x32_i8 on cur regs. SALU computes the per-step scalars.
__global__ __launch_bounds__(512, 2) void conv_gemm(const int8_t* __restrict__ xb,
                                                    const int8_t* __restrict__ Wbr,
                                                    const float* __restrict__ invs,
                                                    float* __restrict__ out) {
  extern __shared__ char smem[];
  int bid = blockIdx.x;
  int swz = (bid & 7) * 112 + (bid >> 3);    // XCD-aware, bijective (896 % 8 == 0)
  int n_img = swz / 14, rg = swz - n_img * 14;
  int y0 = 1 + rg * 4;                       // output rows y0..y0+3 (padded coords)

  int tid = threadIdx.x;
  int ln = tid & 63, wid = tid >> 6;
  int wm = wid >> 2, wn = wid & 3;           // wm: co half, wn: y-row

  size_t xoff = (size_t)n_img * IMG_STRIDE + (size_t)(y0 - 1) * XROW;

  // ---- prologue: stage X once, pure linear copy (6 rows x 14848 B = 89088 B) ----
  #pragma unroll
  for (int i = 0; i < 11; ++i) {
    int o = tid*16 + i*8192;
    if (o < 6*XROW)                          // 89088 = 87*1024: wave-uniform guard
      GLDS(xb + xoff + o, smem + XO + o);
  }

  const int8_t* stSrc = Wbr + tid*16;
  char*         stDst = smem + AO + tid*16;
#define STAGE(SCOFF, BUFQ) do { \
    const int8_t* _s = stSrc + (SCOFF); \
    char* _d = stDst + (BUFQ)*16384; \
    GLDS(_s, _d); GLDS(_s + 8192, _d + 8192); \
  } while (0)

  i32x16 acc[4][2] = {};
  STAGE(0, 0); STAGE(16384, 1); STAGE(32768, 2);

  // invariant read bases
  const char* vA = smem + AO + ((ln >> 5) << 12) + (wm*128 + (ln & 31)) * 16;
  const char* vX = smem + XO + wn*XROW + (ln >> 5)*SROW + ((ln & 31) - 1) * 16;

  i32x4 aA[4][2], bA[2][2], aB[4][2], bB[2][2];

#define LOADF(Q, SU, AV, BV) do { \
    const char* _ab = vA + (Q)*16384; \
    AV[0][0] = *(const i32x4*)(_ab +    0); AV[0][1] = *(const i32x4*)(_ab + 8192); \
    AV[1][0] = *(const i32x4*)(_ab +  512); AV[1][1] = *(const i32x4*)(_ab + 8704); \
    AV[2][0] = *(const i32x4*)(_ab + 1024); AV[2][1] = *(const i32x4*)(_ab + 9216); \
    AV[3][0] = *(const i32x4*)(_ab + 1536); AV[3][1] = *(const i32x4*)(_ab + 9728); \
    const char* _bb = vX + (SU); \
    BV[0][0] = *(const i32x4*)(_bb +    0); BV[0][1] = *(const i32x4*)(_bb + 1856); \
    BV[1][0] = *(const i32x4*)(_bb +  512); BV[1][1] = *(const i32x4*)(_bb + 2368); \
  } while (0)

#define MFMA_ALL(AV, BV) do { \
    __builtin_amdgcn_s_setprio(1); \
    _Pragma("unroll") \
    for (int ks = 0; ks < 2; ++ks) \
      _Pragma("unroll") \
      for (int mt = 0; mt < 4; ++mt) \
        _Pragma("unroll") \
        for (int nt = 0; nt < 2; ++nt) \
          acc[mt][nt] = __builtin_amdgcn_mfma_i32_32x32x32_i8(AV[mt][ks], BV[nt][ks], \
                                                              acc[mt][nt], 0, 0, 0); \
    __builtin_amdgcn_s_setprio(0); \
  } while (0)

#define VMB do { \
    asm volatile("s_waitcnt vmcnt(2)" ::: "memory"); \
    __builtin_amdgcn_s_barrier(); \
  } while (0)

  // prologue wait: X + A(0) landed (A1,A2 = 4 loads outstanding), then block sync
  asm volatile("s_waitcnt vmcnt(4)" ::: "memory");
  __builtin_amdgcn_s_barrier();
  LOADF(0, 0, aA, bA);

  #pragma unroll 1
  for (int t = 0; t < 9; ++t) {
    int kh0 = (t * 11) >> 5,  kw0 = t - kh0*3;
    int t1  = t < 8 ? t + 1 : 8;
    int kh1 = (t1 * 11) >> 5, kw1 = t1 - kh1*3;
    int su0 = kh0*XROW + kw0*16;
    int su1 = su0 + 3712, su2 = su0 + 7424, su3 = su0 + 11136;
    int su4 = kh1*XROW + kw1*16;
    int sA  = 4*t;
    int sc3 = (sA+3 < 36 ? sA+3 : 35) * 16384;
    int sc4 = (sA+4 < 36 ? sA+4 : 35) * 16384;
    int sc5 = (sA+5 < 36 ? sA+5 : 35) * 16384;
    int sc6 = (sA+6 < 36 ? sA+6 : 35) * 16384;

    VMB; STAGE(sc3, 3); LOADF(1, su1, aB, bB); MFMA_ALL(aA, bA);   // step 4t+0
    VMB; STAGE(sc4, 0); LOADF(2, su2, aA, bA); MFMA_ALL(aB, bB);   // step 4t+1
    VMB; STAGE(sc5, 1); LOADF(3, su3, aB, bB); MFMA_ALL(aA, bA);   // step 4t+2
    VMB; STAGE(sc6, 2); LOADF(0, su4, aA, bA); MFMA_ALL(aB, bB);   // step 4t+3
  }
  asm volatile("s_waitcnt vmcnt(0)" ::: "memory");     // drain tail GLDS before exit

  // ---- epilogue: direct coalesced stores. C: col=ln&31 -> xx, row=(r&3)+8(r>>2)+4(ln>>5) ----
  int y_out = y0 + wn - 1;
  size_t ob0 = ((size_t)n_img * COUT) * (HH*WW) + (size_t)y_out * WW;
  #pragma unroll
  for (int mt = 0; mt < 4; ++mt) {
    int cb0 = wm*128 + mt*32 + ((ln >> 5) << 2);
    float4 iv[4];
    #pragma unroll
    for (int q = 0; q < 4; ++q) iv[q] = *(const float4*)(invs + cb0 + 8*q);
    #pragma unroll
    for (int nt = 0; nt < 2; ++nt) {
      int xx = nt*32 + (ln & 31);
      bool ok = (xx >= 1) && (xx <= WW);
      size_t ob = ob0 + (xx - 1);
      #pragma unroll
      for (int r = 0; r < 16; ++r) {
        int q = r >> 2, rr = r & 3;
        int co = cb0 + 8*q + rr;
        float v = fmaxf((float)acc[mt][nt][r] * ((&iv[q].x)[rr]), 0.0f);
        if (ok) out[ob + (size_t)co * (HH*WW)] = v;
      }
    }
  }
}

extern "C" void kernel_launch(void* const* d_in, const int* in_sizes, int n_in,
                              void* d_out, int out_size, void* d_ws, size_t ws_size,
                              hipStream_t stream) {
  const float* x     = (const float*)d_in[0];
  const float* gamma = (const float*)d_in[1];
  const float* beta  = (const float*)d_in[2];
  const float* W     = (const float*)d_in[3];
  float* out = (float*)d_out;

  char* ws = (char*)d_ws;
  // layout: part [262144] | prm [8192] | invs [1024] | Wbr i8 [589824] | pad | xb i8 @1MiB
  double*  part = (double*)ws;
  double*  prm  = (double*)(ws + 262144);
  float*   invs = (float*)(ws + 270336);
  int8_t*  Wbr  = (int8_t*)(ws + 271360);
  int8_t*  xbuf = (int8_t*)(ws + 1048576);
  // xb: 64*58*14848 = 55,115,776 B

  (void)hipFuncSetAttribute((const void*)conv_gemm,
                            hipFuncAttributeMaxDynamicSharedMemorySize, LDS_TOTAL);

  hipLaunchKernelGGL(wrepack,       dim3(256),    dim3(256), 0, stream, W, Wbr, invs);
  hipLaunchKernelGGL(stats_partial, dim3(256*64), dim3(256), 0, stream, x, part);
  hipLaunchKernelGGL(stats_final,   dim3(1),      dim3(256), 0, stream, part, gamma, beta, prm);
  hipLaunchKernelGGL(binarize,      dim3(64*HP),  dim3(256), 0, stream, x, prm, xbuf);
  hipLaunchKernelGGL(conv_gemm,     dim3(896),    dim3(512), LDS_TOTAL, stream, xbuf, Wbr, invs, out);
}

// Round 11
// 270.552 us; speedup vs baseline: 1.5224x; 1.0221x over previous
//
#include <hip/hip_runtime.h>
#include <hip/hip_bf16.h>
#include <stdint.h>

#define HP 58
#define CIN 256
#define COUT 256
#define HH 56
#define WW 56
#define XROW 14848              // bytes per padded row in xb: 16 slots x 58 x 16B
#define IMG_STRIDE (HP*XROW)    // 861184 B per image
#define NPIX 200704.0           // 64*56*56

// conv LDS layout (dynamic, 155136 B):
//   [0,16)           front guard (x_in = -1, slot 0, row 0)
//   [16,89104)       X: 6 rows x 16 slots x 58 x 16B (row stride 14848, slot stride 928)
//   [89104,89600)    tail slack (x_in up to 64 bleeds reads here: discarded outputs)
//   [89600,155136)   A ring: 4 x 16384 ([q4][ks2][co128][16B] per buf)
#define XO    16
#define SROW  928
#define AO    89600
#define LDS_TOTAL 155136

typedef __attribute__((ext_vector_type(4)))  int i32x4;
typedef __attribute__((ext_vector_type(16))) int i32x16;

#define GLDS(g, l) __builtin_amdgcn_global_load_lds( \
    (const __attribute__((address_space(1))) void*)(g), \
    (__attribute__((address_space(3))) void*)(l), 16, 0, 0)

// ---------- K1: per-(channel,image) partial sums in fp64 (deterministic) ----------
__global__ __launch_bounds__(256) void stats_partial(const float* __restrict__ x,
                                                     double* __restrict__ part) {
  int b = blockIdx.x;            // 256*64
  int c = b >> 6, n = b & 63;
  const float4* p = (const float4*)(x + (size_t)(n*CIN + c) * (HH*WW));
  double s = 0.0, s2 = 0.0;
  for (int i = threadIdx.x; i < 784; i += 256) {
    float4 v = p[i];
    double a0 = v.x, a1 = v.y, a2 = v.z, a3 = v.w;
    s  += (a0 + a1) + (a2 + a3);
    s2 += (a0*a0 + a1*a1) + (a2*a2 + a3*a3);
  }
  for (int off = 32; off > 0; off >>= 1) {
    s  += __shfl_down(s, off);
    s2 += __shfl_down(s2, off);
  }
  __shared__ double red[8];
  int wv = threadIdx.x >> 6, ln = threadIdx.x & 63;
  if (ln == 0) { red[wv*2] = s; red[wv*2+1] = s2; }
  __syncthreads();
  if (threadIdx.x == 0) {
    double ts = ((red[0]+red[2])+red[4])+red[6];
    double t2 = ((red[1]+red[3])+red[5])+red[7];
    part[(size_t)(c*64 + n)*2]     = ts;
    part[(size_t)(c*64 + n)*2 + 1] = t2;
  }
}

// ---------- K2: finalize per-channel {mean, gamma*inv_std, beta} in fp64 ----------
__global__ void stats_final(const double* __restrict__ part,
                            const float* __restrict__ gamma,
                            const float* __restrict__ beta,
                            double* __restrict__ prm) {
  int c = threadIdx.x;
  double s = 0.0, s2 = 0.0;
  for (int n = 0; n < 64; ++n) {
    s  += part[(size_t)(c*64+n)*2];
    s2 += part[(size_t)(c*64+n)*2 + 1];
  }
  double mean = s / NPIX;
  double var  = s2 / NPIX - mean*mean;
  double inv  = 1.0 / sqrt(var + 1e-5);
  prm[c*4+0] = mean;
  prm[c*4+1] = (double)gamma[c] * inv;
  prm[c*4+2] = (double)beta[c];
}

// ---------- K3: binarize -> xb[n][y][slot16][x58][16B] int8 ----------
__global__ __launch_bounds__(256) void binarize(const float* __restrict__ x,
                                                const double* __restrict__ prm,
                                                int8_t* __restrict__ xb) {
  int b = blockIdx.x;            // 64*58
  int n = b / HP, y = b % HP;
  int8_t* orow = xb + (size_t)(n*HP + y) * XROW;
  if (y == 0 || y == HP-1) {     // zero padding rows: 14848 B
    int4 z = {0,0,0,0};
    int4* q = (int4*)orow;
    for (int i = threadIdx.x; i < XROW/16; i += 256) q[i] = z;
    return;
  }
  __shared__ char sbuf[WW][260];   // odd dword stride -> conflict-free
  int h  = y - 1;
  int tid = threadIdx.x;
  #pragma unroll
  for (int it = 0; it < 14; ++it) {        // 14*256 = 3584 = 256c * 14 float4
    int t = it*256 + tid;
    int c = t / 14, j = t - c*14;
    float4 v = *(const float4*)(x + (size_t)(n*CIN + c)*(HH*WW) + h*WW + j*4);
    double mu = prm[c*4], gi = prm[c*4+1], be = prm[c*4+2];
    #pragma unroll
    for (int e = 0; e < 4; ++e) {
      double xv = (double)((&v.x)[e]);
      double vv = (xv - mu)*gi + be;
      sbuf[j*4+e][c] = vv > 0.0 ? (int8_t)1 : (vv < 0.0 ? (int8_t)-1 : (int8_t)0);
    }
  }
  __syncthreads();
  for (int u = tid; u < 16*58; u += 256) {
    int slot = u / 58, xx = u - slot*58;
    int4 v = {0,0,0,0};
    if (xx >= 1 && xx <= WW) {
      const uint32_t* src = (const uint32_t*)&sbuf[xx-1][slot*16];
      v.x = src[0]; v.y = src[1]; v.z = src[2]; v.w = src[3];
    }
    *(int4*)(orow + u*16) = v;
  }
}

// ---------- K4: quantize W -> Wbr[tap][h2][q4][ks2][co256][16B] i8, per-co scale ----------
__global__ __launch_bounds__(256) void wrepack(const float* __restrict__ W,
                                               int8_t* __restrict__ Wbr,
                                               float* __restrict__ invs) {
  int co = blockIdx.x, ci = threadIdx.x;
  float w[9]; float mx = 0.f;
  const float* p = W + (size_t)co*(CIN*9) + ci*9;
  #pragma unroll
  for (int t = 0; t < 9; ++t) { w[t] = p[t]; mx = fmaxf(mx, fabsf(w[t])); }
  for (int off = 32; off > 0; off >>= 1) mx = fmaxf(mx, __shfl_xor(mx, off));
  __shared__ float sm[4];
  if ((threadIdx.x & 63) == 0) sm[threadIdx.x >> 6] = mx;
  __syncthreads();
  mx = fmaxf(fmaxf(sm[0], sm[1]), fmaxf(sm[2], sm[3]));
  float s = mx > 0.f ? 127.f / mx : 0.f;
  // ci = h*128 + q*32 + ks*16 + r  ->  off = h*16384 + q*4096 + ks*2048 + co*16 + r
  // NOTE: co halves split across h-tiles of 128co? co is 0..255: each [h] tile holds ALL
  // 256 co? No: tile = 128co per ch. Layout per tap: [h2][q4][ks2][co256][16B] would be
  // 32KB; conv stages 16KB = one (h, ch-half): reorder to [h2][ch2][q4][ks2][co128][16B].
  int h = ci >> 7, q = (ci >> 5) & 3, ks = (ci >> 4) & 1, r = ci & 15;
  int ch = co >> 7, col = co & 127;
  int off = h*32768 + ch*16384 + q*4096 + ks*2048 + col*16 + r;
  #pragma unroll
  for (int t = 0; t < 9; ++t) {
    int qv = (int)lrintf(w[t] * s);
    qv = qv > 127 ? 127 : (qv < -127 ? -127 : qv);
    Wbr[t*65536 + off] = (int8_t)qv;
  }
  if (threadIdx.x == 0) invs[co] = mx / 127.f;
}

// ---------- K5: persistent implicit-GEMM conv, i8 32x32x32, BK=128, 7 tiles/block ----------
// 256 blocks; tile = 128co x 4rows x 64xx; 8 waves = 4wn x 2xh, wave = 128co x 32xx.
// Per step s=tap*2+h (18/tile): vmcnt(2); barrier; STAGE(s+3); LOADF(s+1) (20 ds_read,
// literal offsets); 16 mfma_i32_32x32x32_i8. Tile boundary: lgkm(0)+barrier; stage next
// X + A(0..2) (hidden under epilogue stores); direct coalesced epilogue.
__global__ __launch_bounds__(512, 2) void conv_gemm(const int8_t* __restrict__ xb,
                                                    const int8_t* __restrict__ Wbr,
                                                    const float* __restrict__ invs,
                                                    float* __restrict__ out) {
  extern __shared__ char smem[];
  int bid = blockIdx.x;
  int tid = threadIdx.x;
  int ln = tid & 63, wid = tid >> 6;
  int wn = wid >> 1, xh = wid & 1;           // wn: y-row 0..3, xh: xx half

  // tile-invariant read bases
  const char* vA = smem + AO + ((ln >> 5) << 11) + (ln & 31) * 16;
  const char* vX = smem + XO + wn*XROW + ((ln >> 5))*SROW + (xh*32 + (ln & 31) - 1) * 16;

  const int8_t* stSrcT = Wbr + tid*16;       // + ch*16384 per tile
  char*         stDst  = smem + AO + tid*16;

#define STAGE_X(XOFF) do { \
    _Pragma("unroll") \
    for (int _i = 0; _i < 11; ++_i) { \
      int _o = tid*16 + _i*8192; \
      if (_o < 6*XROW) GLDS(xb + (XOFF) + _o, smem + XO + _o); \
    } \
  } while (0)

#define STAGE_A(CHB, S) do { \
    int _sc = (S) < 18 ? (S) : 17; \
    const int8_t* _s = stSrcT + (CHB) + _sc*32768;  /* tap*65536 + h*32768 */ \
    char* _d = stDst + ((S) & 3)*16384; \
    GLDS(_s, _d); GLDS(_s + 8192, _d + 8192); \
  } while (0)

  i32x4 aA[4][4], bA[4], aB[4][4], bB[4];

#define LOADF(BUF, SU, AV, BV) do { \
    const char* _ab = vA + (BUF)*16384; \
    _Pragma("unroll") \
    for (int _q = 0; _q < 4; ++_q) { \
      AV[_q][0] = *(const i32x4*)(_ab + _q*4096 +    0); \
      AV[_q][1] = *(const i32x4*)(_ab + _q*4096 +  512); \
      AV[_q][2] = *(const i32x4*)(_ab + _q*4096 + 1024); \
      AV[_q][3] = *(const i32x4*)(_ab + _q*4096 + 1536); \
    } \
    const char* _bb = vX + (SU); \
    BV[0] = *(const i32x4*)(_bb +    0); BV[1] = *(const i32x4*)(_bb + 1856); \
    BV[2] = *(const i32x4*)(_bb + 3712); BV[3] = *(const i32x4*)(_bb + 5568); \
  } while (0)

#define MFMA_ALL(AV, BV) do { \
    __builtin_amdgcn_s_setprio(1); \
    _Pragma("unroll") \
    for (int _q = 0; _q < 4; ++_q) \
      _Pragma("unroll") \
      for (int _mt = 0; _mt < 4; ++_mt) \
        acc[_mt] = __builtin_amdgcn_mfma_i32_32x32x32_i8(AV[_q][_mt], BV[_q], acc[_mt], 0, 0, 0); \
    __builtin_amdgcn_s_setprio(0); \
  } while (0)

#define VMB do { \
    asm volatile("s_waitcnt vmcnt(2)" ::: "memory"); \
    __builtin_amdgcn_s_barrier(); \
  } while (0)

  // su helpers per tap (kh*XROW + kw*16), h adds 7424 (=8*SROW)
  const int SUT[9] = { 0*XROW+0*16, 0*XROW+1*16, 0*XROW+2*16,
                       1*XROW+0*16, 1*XROW+1*16, 1*XROW+2*16,
                       2*XROW+0*16, 2*XROW+1*16, 2*XROW+2*16 };

  // first tile prologue
  int T0 = bid*7;
  {
    int ch = T0 / 896, rem = T0 - ch*896;
    int img = rem / 14, rg = rem - img*14;
    size_t xoffp = (size_t)img * IMG_STRIDE + (size_t)(rg*4) * XROW;  // y0-1 = rg*4
    STAGE_X(xoffp);
    int chb = ch*16384;
    STAGE_A(chb, 0); STAGE_A(chb, 1); STAGE_A(chb, 2);
  }

  #pragma unroll 1
  for (int i = 0; i < 7; ++i) {
    int T = bid*7 + i;
    int ch = T / 896, rem = T - ch*896;
    int img = rem / 14, rg = rem - img*14;
    int y0 = 1 + rg*4;
    int chb = ch*16384;

    i32x16 acc[4] = {};

    asm volatile("s_waitcnt vmcnt(4)" ::: "memory");   // X + A(0) landed
    __builtin_amdgcn_s_barrier();
    LOADF(0, SUT[0], aA, bA);

    #pragma unroll 1
    for (int u = 0; u < 9; ++u) {
      int su0 = SUT[u];
      int su1 = su0 + 7424;
      int su2 = (u < 8) ? SUT[u+1] : (SUT[8] + 7424);  // step 2u+2 (clamped geometry)
      int s0 = 2*u;

      VMB; STAGE_A(chb, s0+3); LOADF((s0+1)&3, su1, aB, bB); MFMA_ALL(aA, bA);
      VMB; STAGE_A(chb, s0+4); LOADF((s0+2)&3, su2, aA, bA); MFMA_ALL(aB, bB);
    }

    // tile boundary: all waves' LDS reads complete before restaging X/A
    asm volatile("s_waitcnt lgkmcnt(0)" ::: "memory");
    __builtin_amdgcn_s_barrier();

    if (i < 6) {                                       // stage next tile (hidden by epilogue)
      int Tn = T + 1;
      int chn = Tn / 896, remn = Tn - chn*896;
      int imgn = remn / 14, rgn = remn - imgn*14;
      size_t xoffn = (size_t)imgn * IMG_STRIDE + (size_t)(rgn*4) * XROW;
      STAGE_X(xoffn);
      int chbn = chn*16384;
      STAGE_A(chbn, 0); STAGE_A(chbn, 1); STAGE_A(chbn, 2);
    }

    // epilogue: direct coalesced stores (no LDS)
    int cb0 = ch*128 + ((ln >> 5) << 2);
    int y_out = y0 + wn - 1;
    size_t ob0 = ((size_t)img * COUT) * (HH*WW) + (size_t)y_out * WW;
    int xx = xh*32 + (ln & 31);
    bool ok = (xx >= 1) && (xx <= WW);
    size_t ob = ob0 + (xx - 1);
    #pragma unroll
    for (int mt = 0; mt < 4; ++mt) {
      int cbm = cb0 + mt*32;
      float4 iv[4];
      #pragma unroll
      for (int q = 0; q < 4; ++q) iv[q] = *(const float4*)(invs + cbm + 8*q);
      #pragma unroll
      for (int r = 0; r < 16; ++r) {
        int q = r >> 2, rr = r & 3;
        int co = cbm + 8*q + rr;
        float v = fmaxf((float)acc[mt][r] * ((&iv[q].x)[rr]), 0.0f);
        if (ok) out[ob + (size_t)co * (HH*WW)] = v;
      }
    }
  }
}

extern "C" void kernel_launch(void* const* d_in, const int* in_sizes, int n_in,
                              void* d_out, int out_size, void* d_ws, size_t ws_size,
                              hipStream_t stream) {
  const float* x     = (const float*)d_in[0];
  const float* gamma = (const float*)d_in[1];
  const float* beta  = (const float*)d_in[2];
  const float* W     = (const float*)d_in[3];
  float* out = (float*)d_out;

  char* ws = (char*)d_ws;
  // layout: part [262144] | prm [8192] | invs [1024] | Wbr i8 [589824] | pad | xb i8 @1MiB
  double*  part = (double*)ws;
  double*  prm  = (double*)(ws + 262144);
  float*   invs = (float*)(ws + 270336);
  int8_t*  Wbr  = (int8_t*)(ws + 271360);
  int8_t*  xbuf = (int8_t*)(ws + 1048576);
  // xb: 64*58*14848 = 55,115,776 B

  (void)hipFuncSetAttribute((const void*)conv_gemm,
                            hipFuncAttributeMaxDynamicSharedMemorySize, LDS_TOTAL);

  hipLaunchKernelGGL(wrepack,       dim3(256),    dim3(256), 0, stream, W, Wbr, invs);
  hipLaunchKernelGGL(stats_partial, dim3(256*64), dim3(256), 0, stream, x, part);
  hipLaunchKernelGGL(stats_final,   dim3(1),      dim3(256), 0, stream, part, gamma, beta, prm);
  hipLaunchKernelGGL(binarize,      dim3(64*HP),  dim3(256), 0, stream, x, prm, xbuf);
  hipLaunchKernelGGL(conv_gemm,     dim3(256),    dim3(512), LDS_TOTAL, stream, xbuf, Wbr, invs, out);
}